// Round 1
// 114.555 us; speedup vs baseline: 1.0675x; 1.0675x over previous
//
#include <hip/hip_runtime.h>

// DCNv2, fp32 in/out, all matmul-shaped work on bf16 MFMA.
// Round 1: fuse 4 kernels -> 2.
//  - pre_kernel: x NCHW -> xT_hi/xT_lo bf16 NHWC (split-bf16)  [+ prep of
//    wd A-frags and wo split A-frags in the same launch, blockIdx >= 4096]
//  - fused_dcn_kernel: per 64-px tile: offset conv (im2col GEMM, 3-term
//    split-bf16, fp32-accurate) -> offsets kept in LDS -> bilinear sample
//    -> LDS B-frags -> mfma 16x16x32 deform GEMM.
// ws: xThi 8388608 | xTlo 8388608 | wdA 73728 | woAhi 36864 | woAlo 36864

#define BATCH 4
#define CIN   64
#define COUT  64
#define HH    128
#define WW    128
#define HWPIX (HH*WW)

typedef __attribute__((ext_vector_type(8))) short short8;   // 8 bf16 (4 VGPRs)
typedef __attribute__((ext_vector_type(4))) float floatx4;  // MFMA C/D

__device__ __forceinline__ unsigned short f2bf(float f) {   // RNE f32->bf16
  unsigned int u = __float_as_uint(f);
  unsigned int r = u + 0x7fffu + ((u >> 16) & 1u);
  return (unsigned short)(r >> 16);
}
__device__ __forceinline__ float bf2f(unsigned short h) { return __uint_as_float(((unsigned int)h) << 16); }
__device__ __forceinline__ float lo16f(unsigned int u) { return __uint_as_float(u << 16); }
__device__ __forceinline__ float hi16f(unsigned int u) { return __uint_as_float(u & 0xffff0000u); }

__device__ __forceinline__ unsigned int bilin2(unsigned int u00, unsigned int u01,
                                               unsigned int u10, unsigned int u11,
                                               float w00, float w01, float w10, float w11) {
  float lo = w00 * lo16f(u00) + w01 * lo16f(u01) + w10 * lo16f(u10) + w11 * lo16f(u11);
  float hi = w00 * hi16f(u00) + w01 * hi16f(u01) + w10 * hi16f(u10) + w11 * hi16f(u11);
  return (unsigned int)f2bf(lo) | ((unsigned int)f2bf(hi) << 16);
}

// Fused preprocessing:
//  blocks [0,4096):  x fp32 NCHW -> xThi/xTlo bf16 [b][px][cin]
//  blocks [4096,4312): weight prep
//    wdA[kk][kc2][ct4][lane][j] bf16 (A-frag, 36864 elems);
//    woAhi/lo[kk][kc2][ct2][lane][j] bf16 (A-frag, M=32 rows, rows>=18 zero)
__global__ __launch_bounds__(256) void pre_kernel(const float* __restrict__ x,
                                                  const float* __restrict__ wo,
                                                  const float* __restrict__ wd,
                                                  unsigned short* __restrict__ xThi,
                                                  unsigned short* __restrict__ xTlo,
                                                  unsigned short* __restrict__ wdA,
                                                  unsigned short* __restrict__ woAhi,
                                                  unsigned short* __restrict__ woAlo) {
  int tid = threadIdx.x;
  if (blockIdx.x < 4096) {
    // ---- transpose + split-bf16 ----
    __shared__ float tile[32][33];   // [c_local][p_local]
    int t = blockIdx.x;
    int b = t >> 10, rem = t & 1023;
    int c0 = (rem >> 9) * 32, p0 = (rem & 511) * 32;
    int tx = tid & 31, ty = tid >> 5;      // (32,8)
    const float* xb = x + (size_t)b * CIN * HWPIX;
    size_t boff = (size_t)b * HWPIX * CIN;
#pragma unroll
    for (int i = 0; i < 4; i++)
      tile[ty + i * 8][tx] = xb[(size_t)(c0 + ty + i * 8) * HWPIX + p0 + tx];
    __syncthreads();
#pragma unroll
    for (int i = 0; i < 2; i++) {
      int tt = tid + i * 256;       // 0..511 = 32 rows * 16 cin-pairs
      int row = tt >> 4;
      int cp = tt & 15;
      float v0 = tile[cp * 2][row], v1 = tile[cp * 2 + 1][row];
      unsigned short h0 = f2bf(v0), h1 = f2bf(v1);
      unsigned short l0 = f2bf(v0 - bf2f(h0)), l1 = f2bf(v1 - bf2f(h1));
      size_t o = boff + (size_t)(p0 + row) * CIN + c0 + cp * 2;
      *(ushort2*)&xThi[o] = make_ushort2(h0, h1);
      *(ushort2*)&xTlo[o] = make_ushort2(l0, l1);
    }
  } else {
    // ---- weight prep ----
    int t = (blockIdx.x - 4096) * 256 + tid;
    if (t < 36864) {
      int j = t & 7, lane = (t >> 3) & 63, ct = (t >> 9) & 3, kc = (t >> 11) & 1, kk = t >> 12;
      int cout = ct * 16 + (lane & 15);
      int cin  = kc * 32 + (lane >> 4) * 8 + j;
      wdA[t] = f2bf(wd[(size_t)(cout * CIN + cin) * 9 + kk]);
    }
    int t2 = t - 36864;
    if (t2 >= 0 && t2 < 18432) {
      int j = t2 & 7, lane = (t2 >> 3) & 63, ct = (t2 >> 9) & 1, kc = (t2 >> 10) & 1, kk = t2 >> 11;
      int cout = ct * 16 + (lane & 15);          // conv channel 0..31 (valid < 18)
      int cin  = kc * 32 + (lane >> 4) * 8 + j;
      float v = (cout < 18) ? wo[(size_t)(cout * CIN + cin) * 9 + kk] : 0.f;
      unsigned short h = f2bf(v);
      woAhi[t2] = h;
      woAlo[t2] = f2bf(v - bf2f(h));
    }
  }
}

// Fused offset-conv + deform GEMM. One block = 64 px tile (b, y, x0..x0+63).
// Phase A: offset conv as im2col GEMM (split-bf16 3-term) -> offL in LDS.
// Phase B: bilinear sample (bf16 hi) -> LDS B-frags -> mfma deform GEMM.
// 256 thr = 4 waves; sampling view: p1 = tid>>2 (px), si = tid&3 (16-cin slice).
__global__ __launch_bounds__(256) void fused_dcn_kernel(const unsigned short* __restrict__ xThi,
                                                        const unsigned short* __restrict__ xTlo,
                                                        const unsigned short* __restrict__ woAhi,
                                                        const unsigned short* __restrict__ woAlo,
                                                        const unsigned short* __restrict__ wdA,
                                                        float* __restrict__ out) {
  __shared__ unsigned short sBhi[4096];    // 8 KB; phase A: im2col hi; phase B: sampled B-frags
  __shared__ unsigned short sBlo[4096];    // 8 KB; phase A only: im2col lo
  __shared__ float offL[18 * 64];          // 4.5 KB; offsets for this tile [chan][px_local]

  int tid = threadIdx.x;
  int hw = blockIdx.x;
  int bid = (hw & 7) * 128 + (hw >> 3);    // XCD-contiguous y bands
  int b = bid >> 8, r = bid & 255, y = r >> 1, x0 = (r & 1) << 6;

  int p1 = tid >> 2, si = tid & 3;
  int lane = tid & 63, w = tid >> 6;

  const unsigned short* xhib = xThi + (size_t)b * HWPIX * CIN;
  const unsigned short* xlob = xTlo + (size_t)b * HWPIX * CIN;

  int wq = p1 >> 4, iq = p1 & 15;
  int kcd = si >> 1, qb = si & 1;
  int dst0 = (((wq * 2 + kcd) * 64) + qb * 32 + iq) * 8;
  int dst1 = dst0 + 128;
  int xp = x0 + p1;

  // ================= Phase A: offset conv =================
  floatx4 oacc[2];
  oacc[0] = (floatx4){0.f, 0.f, 0.f, 0.f};
  oacc[1] = (floatx4){0.f, 0.f, 0.f, 0.f};

#pragma unroll 1
  for (int kk = 0; kk < 9; kk++) {
    int ys = y - 1 + kk / 3;
    int xs = xp - 1 + kk % 3;
    bool valid = (ys >= 0) && (ys < HH) && (xs >= 0) && (xs < WW);
    uint4 h0 = {0, 0, 0, 0}, h1 = {0, 0, 0, 0}, l0 = {0, 0, 0, 0}, l1 = {0, 0, 0, 0};
    if (valid) {
      const unsigned short* ph = xhib + (size_t)(ys * WW + xs) * CIN + si * 16;
      const unsigned short* pl = xlob + (size_t)(ys * WW + xs) * CIN + si * 16;
      h0 = *(const uint4*)ph; h1 = *(const uint4*)(ph + 8);
      l0 = *(const uint4*)pl; l1 = *(const uint4*)(pl + 8);
    }
    *(uint4*)&sBhi[dst0] = h0; *(uint4*)&sBhi[dst1] = h1;
    *(uint4*)&sBlo[dst0] = l0; *(uint4*)&sBlo[dst1] = l1;
    __syncthreads();
    short8 bh0 = *(const short8*)&sBhi[(w * 2 + 0) * 512 + lane * 8];
    short8 bh1 = *(const short8*)&sBhi[(w * 2 + 1) * 512 + lane * 8];
    short8 bl0 = *(const short8*)&sBlo[(w * 2 + 0) * 512 + lane * 8];
    short8 bl1 = *(const short8*)&sBlo[(w * 2 + 1) * 512 + lane * 8];
    const short8* Ah = (const short8*)(woAhi + (size_t)kk * 2048);
    const short8* Al = (const short8*)(woAlo + (size_t)kk * 2048);
#pragma unroll
    for (int ct = 0; ct < 2; ct++) {
      short8 ah0 = Ah[ct * 64 + lane], ah1 = Ah[128 + ct * 64 + lane];
      short8 al0 = Al[ct * 64 + lane], al1 = Al[128 + ct * 64 + lane];
      oacc[ct] = __builtin_amdgcn_mfma_f32_16x16x32_bf16(ah0, bh0, oacc[ct], 0, 0, 0);
      oacc[ct] = __builtin_amdgcn_mfma_f32_16x16x32_bf16(ah0, bl0, oacc[ct], 0, 0, 0);
      oacc[ct] = __builtin_amdgcn_mfma_f32_16x16x32_bf16(al0, bh0, oacc[ct], 0, 0, 0);
      oacc[ct] = __builtin_amdgcn_mfma_f32_16x16x32_bf16(ah1, bh1, oacc[ct], 0, 0, 0);
      oacc[ct] = __builtin_amdgcn_mfma_f32_16x16x32_bf16(ah1, bl1, oacc[ct], 0, 0, 0);
      oacc[ct] = __builtin_amdgcn_mfma_f32_16x16x32_bf16(al1, bh1, oacc[ct], 0, 0, 0);
    }
    __syncthreads();
  }

  // Scatter offsets to LDS: D layout col=lane&15 (px), row=(lane>>4)*4+rr (chan)
  {
    int pxl = w * 16 + (lane & 15);
    int rowb = (lane >> 4) * 4;
#pragma unroll
    for (int ct = 0; ct < 2; ct++)
#pragma unroll
      for (int rr = 0; rr < 4; rr++) {
        int row = ct * 16 + rowb + rr;
        if (row < 18) offL[row * 64 + pxl] = oacc[ct][rr];
      }
  }
  __syncthreads();

  // ================= Phase B: deform sample + GEMM =================
  floatx4 acc[4];
#pragma unroll
  for (int ct = 0; ct < 4; ct++) acc[ct] = (floatx4){0.f, 0.f, 0.f, 0.f};

#pragma unroll 1
  for (int kk = 0; kk < 9; kk++) {
    // ---- phase 1: sample 16 cin for (px=p1) ----
    {
      float dy = offL[(2 * kk) * 64 + p1];
      float dx = offL[(2 * kk + 1) * 64 + p1];
      float ys = (float)(y - 1 + kk / 3) + dy;
      float xs = (float)(xp - 1 + kk % 3) + dx;
      float y0f = floorf(ys), x0f = floorf(xs);
      float wy = ys - y0f, wx = xs - x0f;
      int iy0 = (int)y0f, ix0 = (int)x0f;
      int iy1 = iy0 + 1, ix1 = ix0 + 1;
      float w00 = (1.f - wy) * (1.f - wx), w01 = (1.f - wy) * wx;
      float w10 = wy * (1.f - wx), w11 = wy * wx;
      bool vy0 = (iy0 >= 0) && (iy0 < HH), vy1 = (iy1 >= 0) && (iy1 < HH);
      bool vx0 = (ix0 >= 0) && (ix0 < WW), vx1 = (ix1 >= 0) && (ix1 < WW);
      if (!(vy0 && vx0)) w00 = 0.f;
      if (!(vy0 && vx1)) w01 = 0.f;
      if (!(vy1 && vx0)) w10 = 0.f;
      if (!(vy1 && vx1)) w11 = 0.f;
      int cy0 = min(max(iy0, 0), HH - 1), cy1 = min(max(iy1, 0), HH - 1);
      int cx0 = min(max(ix0, 0), WW - 1), cx1 = min(max(ix1, 0), WW - 1);
      const unsigned short* q00 = xhib + (size_t)(cy0 * WW + cx0) * CIN + si * 16;
      const unsigned short* q01 = xhib + (size_t)(cy0 * WW + cx1) * CIN + si * 16;
      const unsigned short* q10 = xhib + (size_t)(cy1 * WW + cx0) * CIN + si * 16;
      const unsigned short* q11 = xhib + (size_t)(cy1 * WW + cx1) * CIN + si * 16;
      uint4 a00 = *(const uint4*)q00, a01 = *(const uint4*)q01;
      uint4 a10 = *(const uint4*)q10, a11 = *(const uint4*)q11;
      uint4 b00 = *(const uint4*)(q00 + 8), b01 = *(const uint4*)(q01 + 8);
      uint4 b10 = *(const uint4*)(q10 + 8), b11 = *(const uint4*)(q11 + 8);
      uint4 o0, o1;
      o0.x = bilin2(a00.x, a01.x, a10.x, a11.x, w00, w01, w10, w11);
      o0.y = bilin2(a00.y, a01.y, a10.y, a11.y, w00, w01, w10, w11);
      o0.z = bilin2(a00.z, a01.z, a10.z, a11.z, w00, w01, w10, w11);
      o0.w = bilin2(a00.w, a01.w, a10.w, a11.w, w00, w01, w10, w11);
      o1.x = bilin2(b00.x, b01.x, b10.x, b11.x, w00, w01, w10, w11);
      o1.y = bilin2(b00.y, b01.y, b10.y, b11.y, w00, w01, w10, w11);
      o1.z = bilin2(b00.z, b01.z, b10.z, b11.z, w00, w01, w10, w11);
      o1.w = bilin2(b00.w, b01.w, b10.w, b11.w, w00, w01, w10, w11);
      *(uint4*)&sBhi[dst0] = o0;
      *(uint4*)&sBhi[dst1] = o1;
    }
    __syncthreads();
    // ---- phase 2: MFMA ----
    {
      short8 bv0 = *(const short8*)&sBhi[(w * 2 + 0) * 512 + lane * 8];
      short8 bv1 = *(const short8*)&sBhi[(w * 2 + 1) * 512 + lane * 8];
      const short8* Ap = (const short8*)(wdA + (size_t)kk * 4096);
#pragma unroll
      for (int ct = 0; ct < 4; ct++) {
        short8 a0 = Ap[ct * 64 + lane];
        short8 a1 = Ap[256 + ct * 64 + lane];
        acc[ct] = __builtin_amdgcn_mfma_f32_16x16x32_bf16(a0, bv0, acc[ct], 0, 0, 0);
        acc[ct] = __builtin_amdgcn_mfma_f32_16x16x32_bf16(a1, bv1, acc[ct], 0, 0, 0);
      }
    }
    __syncthreads();
  }

  // D: col = lane&15 (px in wave tile), row = (lane>>4)*4 + reg (cout in ct tile)
  int px = x0 + w * 16 + (lane & 15);
  int rowb = (lane >> 4) * 4;
  float* outb = out + (size_t)b * COUT * HWPIX + y * WW + px;
#pragma unroll
  for (int ct = 0; ct < 4; ct++)
#pragma unroll
    for (int rr = 0; rr < 4; rr++)
      outb[(size_t)(ct * 16 + rowb + rr) * HWPIX] = acc[ct][rr];
}

extern "C" void kernel_launch(void* const* d_in, const int* in_sizes, int n_in,
                              void* d_out, int out_size, void* d_ws, size_t ws_size,
                              hipStream_t stream) {
  const float* x  = (const float*)d_in[0];
  const float* wo = (const float*)d_in[1];
  const float* wd = (const float*)d_in[2];
  float* out = (float*)d_out;

  char* wsb = (char*)d_ws;
  unsigned short* xThi  = (unsigned short*)wsb;                         // 8,388,608 B
  unsigned short* xTlo  = (unsigned short*)(wsb + 8388608);             // 8,388,608 B
  unsigned short* wdA   = (unsigned short*)(wsb + 16777216);            // 73,728 B
  unsigned short* woAhi = (unsigned short*)(wsb + 16777216 + 73728);    // 36,864 B
  unsigned short* woAlo = (unsigned short*)(wsb + 16850944 + 36864);    // 36,864 B

  pre_kernel<<<dim3(4096 + 216), dim3(256), 0, stream>>>(x, wo, wd, xThi, xTlo, wdA, woAhi, woAlo);
  fused_dcn_kernel<<<dim3(BATCH * HWPIX / 64), dim3(256), 0, stream>>>(xThi, xTlo, woAhi, woAlo, wdA, out);
}